// Round 1
// baseline (196.127 us; speedup 1.0000x reference)
//
#include <hip/hip_runtime.h>

// Reference analysis: out = ((v0*DECAY + s) * (1 - ((v0*DECAY + s) > T)) > T)
// is identically 0 for all inputs (incl. NaN): if v > T the reset zeroes it
// (0 > 0.5 false); if v <= T the strict compare fails. So this kernel is a
// pure zero-fill of d_out (32*4096*256 fp32 = 128 MiB). Write-only HBM bound.

__global__ void OutputLayer_3100966388047_kernel(float4* __restrict__ out, int n4) {
    int i = blockIdx.x * blockDim.x + threadIdx.x;
    if (i < n4) {
        out[i] = make_float4(0.0f, 0.0f, 0.0f, 0.0f);
    }
}

extern "C" void kernel_launch(void* const* d_in, const int* in_sizes, int n_in,
                              void* d_out, int out_size, void* d_ws, size_t ws_size,
                              hipStream_t stream) {
    (void)d_in; (void)in_sizes; (void)n_in; (void)d_ws; (void)ws_size;
    // out_size = 33,554,432 (divisible by 4) -> 8,388,608 float4 stores
    int n4 = out_size / 4;
    const int block = 256;
    int grid = (n4 + block - 1) / block;
    OutputLayer_3100966388047_kernel<<<grid, block, 0, stream>>>((float4*)d_out, n4);
}